// Round 1
// baseline (1031.341 us; speedup 1.0000x reference)
//
#include <hip/hip_runtime.h>

#define MDIM 49152
#define BDIM 256
#define DDIM 2048
#define PDIM 8192
#define NCAMS 6
#define INV_BETA 20.0f

typedef __attribute__((ext_vector_type(8))) short bf16x8;
typedef __attribute__((ext_vector_type(4))) float f32x4;

static __device__ __forceinline__ unsigned short f2bf(float f) {
  unsigned u = __float_as_uint(f);
  unsigned r = 0x7FFFu + ((u >> 16) & 1u);
  return (unsigned short)((u + r) >> 16);
}

// monotonic float->uint mapping (larger float => larger uint)
static __device__ __forceinline__ unsigned f2u(float f) {
  unsigned u = __float_as_uint(f);
  return (u & 0x80000000u) ? ~u : (u | 0x80000000u);
}

// ---------------------------------------------------------------- GEMM ----
// sims[b][m] = dot(features[b,:], bank[m,:])  (NT layout, both K-contiguous)
__global__ __launch_bounds__(256) void gemm_kernel(
    const float* __restrict__ feat, const float* __restrict__ bank,
    float* __restrict__ sims)
{
  __shared__ unsigned short As[128][64];   // 16 KB bf16
  __shared__ unsigned short Bs[128][64];   // 16 KB bf16

  const int colTile = blockIdx.x * 128;    // bank rows
  const int rowTile = blockIdx.y * 128;    // feature rows
  const int t = threadIdx.x;
  const int lane = t & 63;
  const int wave = t >> 6;
  const int wm = (wave & 1) * 64;
  const int wn = (wave >> 1) * 64;
  const int fr = lane & 15;
  const int quad = lane >> 4;

  const int tr = t >> 4;          // 0..15 (row within staging pass)
  const int tkf = (t & 15) * 4;   // float offset 0..60

  f32x4 acc[4][4];
  #pragma unroll
  for (int i = 0; i < 4; ++i)
    #pragma unroll
    for (int j = 0; j < 4; ++j)
      acc[i][j] = (f32x4){0.f, 0.f, 0.f, 0.f};

  for (int kc = 0; kc < DDIM; kc += 64) {
    // stage fp32 -> bf16 into LDS (coalesced float4, conflict-free ds_write_b64)
    #pragma unroll
    for (int p = 0; p < 8; ++p) {
      const int r = p * 16 + tr;
      const float4 va = *(const float4*)(feat + (size_t)(rowTile + r) * DDIM + kc + tkf);
      ushort4 pa; pa.x = f2bf(va.x); pa.y = f2bf(va.y); pa.z = f2bf(va.z); pa.w = f2bf(va.w);
      *(ushort4*)(&As[r][tkf]) = pa;
      const float4 vb = *(const float4*)(bank + (size_t)(colTile + r) * DDIM + kc + tkf);
      ushort4 pb; pb.x = f2bf(vb.x); pb.y = f2bf(vb.y); pb.z = f2bf(vb.z); pb.w = f2bf(vb.w);
      *(ushort4*)(&Bs[r][tkf]) = pb;
    }
    __syncthreads();
    #pragma unroll
    for (int kk = 0; kk < 64; kk += 32) {
      bf16x8 fa[4], fb[4];
      #pragma unroll
      for (int i = 0; i < 4; ++i)
        fa[i] = *(const bf16x8*)(&As[wm + i * 16 + fr][kk + quad * 8]);
      #pragma unroll
      for (int j = 0; j < 4; ++j)
        fb[j] = *(const bf16x8*)(&Bs[wn + j * 16 + fr][kk + quad * 8]);
      #pragma unroll
      for (int i = 0; i < 4; ++i)
        #pragma unroll
        for (int j = 0; j < 4; ++j)
          acc[i][j] = __builtin_amdgcn_mfma_f32_16x16x32_bf16(fa[i], fb[j], acc[i][j], 0, 0, 0);
    }
    __syncthreads();
  }

  #pragma unroll
  for (int i = 0; i < 4; ++i) {
    const int row0 = rowTile + wm + i * 16 + quad * 4;
    #pragma unroll
    for (int j = 0; j < 4; ++j) {
      const int col = colTile + wn + j * 16 + fr;
      #pragma unroll
      for (int r = 0; r < 4; ++r)
        sims[(size_t)(row0 + r) * MDIM + col] = acc[i][j][r];
    }
  }
}

// ------------------------------------------------------- block reductions ----
static __device__ __forceinline__ float blk_max(float v, float* buf, int t) {
  buf[t] = v; __syncthreads();
  for (int s = 128; s > 0; s >>= 1) {
    if (t < s) buf[t] = fmaxf(buf[t], buf[t + s]);
    __syncthreads();
  }
  const float r = buf[0]; __syncthreads();
  return r;
}

static __device__ __forceinline__ float blk_sum(float v, float* buf, int t) {
  buf[t] = v; __syncthreads();
  for (int s = 128; s > 0; s >>= 1) {
    if (t < s) buf[t] += buf[t + s];
    __syncthreads();
  }
  const float r = buf[0]; __syncthreads();
  return r;
}

static __device__ __forceinline__ void blk_argmax(float v, int idx, float* buf, int* ibuf,
                                                  int t, float& mv, int& mi) {
  buf[t] = v; ibuf[t] = idx; __syncthreads();
  for (int s = 128; s > 0; s >>= 1) {
    if (t < s) {
      const float v2 = buf[t + s]; const int i2 = ibuf[t + s];
      if (v2 > buf[t] || (v2 == buf[t] && i2 < ibuf[t])) { buf[t] = v2; ibuf[t] = i2; }
    }
    __syncthreads();
  }
  mv = buf[0]; mi = ibuf[0]; __syncthreads();
}

// exact k-th largest value of row (excluding 6 indices), 4x8-bit radix select
static __device__ __forceinline__ float radix_kth_top(
    const float* __restrict__ row, unsigned k, const int* excl,
    unsigned* hist, unsigned* sh, int t)
{
  unsigned prefix = 0;
  unsigned need = k;
  for (int pass = 0; pass < 4; ++pass) {
    const int shift = 24 - pass * 8;
    hist[t] = 0;
    __syncthreads();
    const unsigned pmask = pass ? (0xFFFFFFFFu << (shift + 8)) : 0u;
    for (int i = t; i < MDIM; i += 256) {
      bool ex = false;
      #pragma unroll
      for (int e = 0; e < 6; ++e) ex = ex || (i == excl[e]);
      if (ex) continue;
      const unsigned u = f2u(row[i]);
      if ((u & pmask) == prefix) atomicAdd(&hist[(u >> shift) & 0xFFu], 1u);
    }
    __syncthreads();
    if (t == 0) {
      unsigned cum = 0; int bsel = 0;
      for (int bb = 255; bb >= 0; --bb) {
        const unsigned c = hist[bb];
        if (cum + c >= need) { bsel = bb; break; }
        cum += c;
      }
      sh[0] = prefix | ((unsigned)bsel << shift);
      sh[1] = need - cum;
    }
    __syncthreads();
    prefix = sh[0];
    need = sh[1];
    __syncthreads();
  }
  unsigned u = prefix;
  u = (u & 0x80000000u) ? (u & 0x7FFFFFFFu) : ~u;
  return __uint_as_float(u);
}

// S = sum_{top-k values, excluding excl-indices} exp((v-m)/beta), exact under ties
static __device__ __forceinline__ float topk_sumexp(
    const float* __restrict__ row, float m, float thr, unsigned k,
    const int* excl, float* buf, int t)
{
  const unsigned tu = f2u(thr);
  float s = 0.f, c = 0.f;
  for (int i = t; i < MDIM; i += 256) {
    bool ex = false;
    #pragma unroll
    for (int e = 0; e < 6; ++e) ex = ex || (i == excl[e]);
    if (ex) continue;
    const float v = row[i];
    if (f2u(v) > tu) { s += __expf((v - m) * INV_BETA); c += 1.f; }
  }
  const float St = blk_sum(s, buf, t);
  const float Ct = blk_sum(c, buf, t);
  return St + ((float)k - Ct) * __expf((thr - m) * INV_BETA);
}

// ------------------------------------------------------------ per-row ----
__global__ __launch_bounds__(256) void row_kernel(
    const float* __restrict__ sims, const int* __restrict__ plabel,
    const int* __restrict__ proxy, const int* __restrict__ cams,
    const int* __restrict__ assoc, float* __restrict__ losses)
{
  __shared__ float sbuf[256];
  __shared__ int sibuf[256];
  __shared__ unsigned hist[256];
  __shared__ unsigned ssh[2];
  __shared__ float scv[NCAMS];
  __shared__ int sci[NCAMS];
  __shared__ float spv[3];
  __shared__ int spi[3];

  const int b = blockIdx.x;
  const int part = blockIdx.y;
  const int t = threadIdx.x;
  const float* row = sims + (size_t)b * MDIM;

  if (part == 0) {
    // CE over own camera block
    const int base = cams[b] * PDIM;
    float lm = -3.4e38f;
    for (int i = t; i < PDIM; i += 256) lm = fmaxf(lm, row[base + i]);
    const float m = blk_max(lm, sbuf, t);
    float ls = 0.f;
    for (int i = t; i < PDIM; i += 256) ls += __expf((row[base + i] - m) * INV_BETA);
    const float S = blk_sum(ls, sbuf, t);
    if (t == 0)
      losses[b] = m * INV_BETA + __logf(S) - row[proxy[b]] * INV_BETA;
  } else if (part == 1) {
    // associate loss: 6 assoc logits + top-50 hard negatives (assoc excluded)
    int a6[6];
    const int* ar = assoc + (size_t)plabel[b] * 6;
    #pragma unroll
    for (int e = 0; e < 6; ++e) a6[e] = ar[e];
    float lm = -3.4e38f;
    for (int i = t; i < MDIM; i += 256) lm = fmaxf(lm, row[i]);
    const float m = blk_max(lm, sbuf, t);   // row max == max of the 56-cat (assoc values re-enter)
    const float thr = radix_kth_top(row, 50u, a6, hist, ssh, t);
    float S = topk_sumexp(row, m, thr, 50u, a6, sbuf, t);
    if (t == 0) {
      float am = 0.f;
      #pragma unroll
      for (int e = 0; e < 6; ++e) {
        const float v = row[a6[e]];
        S += __expf((v - m) * INV_BETA);
        am += v;
      }
      losses[BDIM + b] = m * INV_BETA + __logf(S) - am * (INV_BETA / 6.0f);
    }
  } else {
    // online loss: per-cam argmax tops, top-3 positives, +30 hard negatives
    #pragma unroll
    for (int c = 0; c < NCAMS; ++c) {
      float lm = -3.4e38f; int li = c * PDIM;
      for (int i = t; i < PDIM; i += 256) {
        const float v = row[c * PDIM + i];
        if (v > lm) { lm = v; li = c * PDIM + i; }
      }
      float mv; int mi;
      blk_argmax(lm, li, sbuf, sibuf, t, mv, mi);
      if (t == 0) { scv[c] = mv; sci[c] = mi; }
    }
    if (t == 0) {
      unsigned used = 0;
      for (int r = 0; r < 3; ++r) {
        int best = -1; float bv = -3.4e38f;
        for (int c = 0; c < NCAMS; ++c)
          if (!((used >> c) & 1u) && scv[c] > bv) { bv = scv[c]; best = c; }
        used |= 1u << best;
        spv[r] = scv[best]; spi[r] = sci[best];
      }
    }
    __syncthreads();
    const float p0 = spv[0], p1 = spv[1], p2 = spv[2];
    int ex[6];
    ex[0] = spi[0]; ex[1] = spi[1]; ex[2] = spi[2];
    ex[3] = spi[0]; ex[4] = spi[0]; ex[5] = spi[0];
    const float m = p0;                      // global row max is a cam top -> pos[0]
    const float thr = radix_kth_top(row, 30u, ex, hist, ssh, t);
    float S = topk_sumexp(row, m, thr, 30u, ex, sbuf, t);
    if (t == 0) {
      S += 1.0f + __expf((p1 - m) * INV_BETA) + __expf((p2 - m) * INV_BETA);
      losses[2 * BDIM + b] = m * INV_BETA + __logf(S) - (p0 + p1 + p2) * (INV_BETA / 3.0f);
    }
  }
}

// ----------------------------------------------------------- finalize ----
__global__ __launch_bounds__(256) void final_kernel(
    const float* __restrict__ losses, const int* __restrict__ cams,
    float* __restrict__ out)
{
  __shared__ float s0[NCAMS], s1[NCAMS], s2[NCAMS];
  __shared__ int cnt[NCAMS];
  const int t = threadIdx.x;
  if (t < NCAMS) { s0[t] = 0.f; s1[t] = 0.f; s2[t] = 0.f; cnt[t] = 0; }
  __syncthreads();
  const int c = cams[t];
  atomicAdd(&s0[c], losses[t]);
  atomicAdd(&s1[c], losses[BDIM + t]);
  atomicAdd(&s2[c], losses[2 * BDIM + t]);
  atomicAdd(&cnt[c], 1);
  __syncthreads();
  if (t == 0) {
    float L = 0.f;
    for (int i = 0; i < NCAMS; ++i) {
      if (cnt[i] > 0) {
        const float ic = 1.0f / (float)cnt[i];
        L += 0.6f * s0[i] * ic + 0.7f * s1[i] * ic + 0.7f * s2[i] * ic;
      }
    }
    out[0] = L;
  }
}

extern "C" void kernel_launch(void* const* d_in, const int* in_sizes, int n_in,
                              void* d_out, int out_size, void* d_ws, size_t ws_size,
                              hipStream_t stream) {
  const float* feat   = (const float*)d_in[0];
  const float* bank   = (const float*)d_in[1];
  const int*   plabel = (const int*)d_in[2];
  const int*   proxy  = (const int*)d_in[3];
  const int*   cams   = (const int*)d_in[4];
  const int*   assoc  = (const int*)d_in[5];
  float* out = (float*)d_out;

  float* sims   = (float*)d_ws;                         // 256*49152 fp32 = 50.3 MB
  float* losses = sims + (size_t)BDIM * MDIM;           // 3*256 fp32

  gemm_kernel<<<dim3(MDIM / 128, BDIM / 128), 256, 0, stream>>>(feat, bank, sims);
  row_kernel<<<dim3(BDIM, 3), 256, 0, stream>>>(sims, plabel, proxy, cams, assoc, losses);
  final_kernel<<<1, 256, 0, stream>>>(losses, cams, out);
}

// Round 2
// 668.763 us; speedup vs baseline: 1.5422x; 1.5422x over previous
//
#include <hip/hip_runtime.h>

#define MDIM 49152
#define BDIM 256
#define DDIM 2048
#define PDIM 8192
#define NCAMS 6
#define INV_BETA 20.0f
#define UFILT 0xBFC00000u   /* f2u(1.5f): histogram pre-filter; top-56 sits near 3.2 sigma */

typedef __attribute__((ext_vector_type(8))) short bf16x8;
typedef __attribute__((ext_vector_type(4))) float f32x4;

static __device__ __forceinline__ unsigned short f2bf(float f) {
  unsigned u = __float_as_uint(f);
  unsigned r = 0x7FFFu + ((u >> 16) & 1u);
  return (unsigned short)((u + r) >> 16);
}

// monotonic float->uint (larger float => larger uint), and inverse
static __device__ __forceinline__ unsigned f2u(float f) {
  unsigned u = __float_as_uint(f);
  return (u & 0x80000000u) ? ~u : (u | 0x80000000u);
}
static __device__ __forceinline__ float u2f(unsigned u) {
  return __uint_as_float((u & 0x80000000u) ? (u & 0x7FFFFFFFu) : ~u);
}

static __device__ __forceinline__ void gload_lds16(void* lds, const void* g) {
  __builtin_amdgcn_global_load_lds((const __attribute__((address_space(1))) unsigned int*)g,
                                   (__attribute__((address_space(3))) unsigned int*)lds,
                                   16, 0, 0);
}

// ------------------------------------------------ feat fp32 -> bf16 ----
__global__ __launch_bounds__(256) void conv_feat(
    const float* __restrict__ feat, unsigned short* __restrict__ fb)
{
  const int i = (blockIdx.x * 256 + threadIdx.x) * 4;
  const float4 v = *(const float4*)(feat + i);
  ushort4 p;
  p.x = f2bf(v.x); p.y = f2bf(v.y); p.z = f2bf(v.z); p.w = f2bf(v.w);
  *(ushort4*)(fb + i) = p;
}

// ---------------------------------------------------------------- GEMM ----
// sims[b][m] = feat[b,:] . bank[m,:].  BM=256 (all rows, bank read ONCE),
// BN=64, BK=64.  A staged bf16 via global_load_lds(16B); B cvt in-register.
__global__ __launch_bounds__(256) void gemm_kernel(
    const unsigned short* __restrict__ featb, const float* __restrict__ bank,
    float* __restrict__ sims)
{
  __shared__ unsigned short As[256][64];   // 32 KB
  __shared__ unsigned short Bs[64][64];    // 8 KB

  const int colTile = blockIdx.x * 64;     // bank rows
  const int t = threadIdx.x;
  const int lane = t & 63;
  const int w = t >> 6;                    // wave 0..3 -> rows [w*64, w*64+64)
  const int fr = lane & 15;
  const int quad = lane >> 4;
  const int tr = t >> 4;                   // 0..15
  const int tkf = (t & 15) * 4;            // float col offset

  const int arow = w * 64 + (lane >> 3);   // + q*8
  const int acol = (lane & 7) * 8;         // bf16 col offset (16B granules)

  f32x4 acc[4][4];
  #pragma unroll
  for (int i = 0; i < 4; ++i)
    #pragma unroll
    for (int j = 0; j < 4; ++j)
      acc[i][j] = (f32x4){0.f, 0.f, 0.f, 0.f};

  for (int kc = 0; kc < DDIM; kc += 64) {
    // A: each wave DMAs its own 64x64 bf16 sub-tile, 8 x 1KB issues
    #pragma unroll
    for (int q = 0; q < 8; ++q) {
      const unsigned short* g = featb + (size_t)(arow + q * 8) * DDIM + kc + acol;
      gload_lds16(&As[w * 64 + q * 8][0], g);
    }
    // B: 64x64 fp32 -> bf16 (register cvt)
    #pragma unroll
    for (int p = 0; p < 4; ++p) {
      const int r = p * 16 + tr;
      const float4 vb = *(const float4*)(bank + (size_t)(colTile + r) * DDIM + kc + tkf);
      ushort4 pb; pb.x = f2bf(vb.x); pb.y = f2bf(vb.y); pb.z = f2bf(vb.z); pb.w = f2bf(vb.w);
      *(ushort4*)(&Bs[r][tkf]) = pb;
    }
    __syncthreads();
    #pragma unroll
    for (int kk = 0; kk < 64; kk += 32) {
      bf16x8 fa[4], fb[4];
      #pragma unroll
      for (int i = 0; i < 4; ++i)
        fa[i] = *(const bf16x8*)(&As[w * 64 + i * 16 + fr][kk + quad * 8]);
      #pragma unroll
      for (int j = 0; j < 4; ++j)
        fb[j] = *(const bf16x8*)(&Bs[j * 16 + fr][kk + quad * 8]);
      #pragma unroll
      for (int i = 0; i < 4; ++i)
        #pragma unroll
        for (int j = 0; j < 4; ++j)
          acc[i][j] = __builtin_amdgcn_mfma_f32_16x16x32_bf16(fa[i], fb[j], acc[i][j], 0, 0, 0);
    }
    __syncthreads();
  }

  #pragma unroll
  for (int i = 0; i < 4; ++i) {
    const int row0 = w * 64 + i * 16 + quad * 4;
    #pragma unroll
    for (int j = 0; j < 4; ++j) {
      const int col = colTile + j * 16 + fr;
      #pragma unroll
      for (int r = 0; r < 4; ++r)
        sims[(size_t)(row0 + r) * MDIM + col] = acc[i][j][r];
    }
  }
}

// ------------------------------------------------------------ per-row ----
static __device__ __forceinline__ float blk_sum1024(float v, float* buf, int t) {
  buf[t] = v; __syncthreads();
  for (int s = 512; s > 0; s >>= 1) {
    if (t < s) buf[t] += buf[t + s];
    __syncthreads();
  }
  const float r = buf[0]; __syncthreads();
  return r;
}

// One block (1024 thr) per row: 2 vectorized scans -> all three losses.
__global__ __launch_bounds__(1024) void row_kernel(
    const float* __restrict__ sims, const int* __restrict__ plabel,
    const int* __restrict__ proxy, const int* __restrict__ cams,
    const int* __restrict__ assoc, float* __restrict__ losses)
{
  __shared__ unsigned hist[4][2048];       // 32 KB, 4 privatized copies
  __shared__ unsigned candU[1024];         // 4 KB
  __shared__ int candI[1024];              // 4 KB
  __shared__ unsigned ubuf[1024];          // 4 KB (suffix scan)
  __shared__ float rbuf[1024];             // 4 KB (reductions)
  __shared__ unsigned long long camKey[NCAMS];
  __shared__ unsigned scnt;
  __shared__ int selB;
  __shared__ float sPv[3];
  __shared__ int sPi[3];
  __shared__ float sM;

  const int b = blockIdx.x;
  const int t = threadIdx.x;
  const float* row = sims + (size_t)b * MDIM;

  for (int i = t; i < 4 * 2048; i += 1024) ((unsigned*)hist)[i] = 0u;
  if (t < NCAMS) camKey[t] = 0ull;
  if (t == 0) { scnt = 0u; selB = 0; }
  __syncthreads();

  // ---- scan 1: histogram (filtered) + per-cam argmax ----
  const int copy = t >> 8;
  unsigned cmU[NCAMS] = {0, 0, 0, 0, 0, 0};
  int cmI[NCAMS] = {0, 0, 0, 0, 0, 0};
  #pragma unroll
  for (int it = 0; it < 12; ++it) {
    const int i = t * 4 + it * 4096;
    const float4 v = *(const float4*)(row + i);
    const float vv[4] = {v.x, v.y, v.z, v.w};
    unsigned bu = 0; int bi = i;
    #pragma unroll
    for (int e = 0; e < 4; ++e) {
      const unsigned u = f2u(vv[e]);
      if (u > UFILT) {
        atomicAdd(&hist[copy][u >> 21], 1u);
        if (u > bu) { bu = u; bi = i + e; }
      }
    }
    if (bu) {
      const int c = i >> 13;               // cam uniform within a float4
      #pragma unroll
      for (int cc = 0; cc < NCAMS; ++cc)
        if (cc == c && bu > cmU[cc]) { cmU[cc] = bu; cmI[cc] = bi; }
    }
  }
  #pragma unroll
  for (int cc = 0; cc < NCAMS; ++cc)
    if (cmU[cc])
      atomicMax(&camKey[cc],
                ((unsigned long long)cmU[cc] << 32) |
                (unsigned long long)(0xFFFFFFFFu - (unsigned)cmI[cc]));
  __syncthreads();

  // ---- positives: top-3 cam maxima (value desc, lower index on ties) ----
  if (t == 0) {
    unsigned long long k[NCAMS];
    #pragma unroll
    for (int c = 0; c < NCAMS; ++c) k[c] = camKey[c];
    unsigned used = 0;
    for (int r = 0; r < 3; ++r) {
      int best = 0; unsigned long long bv = 0ull;
      for (int c = 0; c < NCAMS; ++c)
        if (!((used >> c) & 1u) && k[c] > bv) { bv = k[c]; best = c; }
      used |= 1u << best;
      sPv[r] = u2f((unsigned)(bv >> 32));
      sPi[r] = (int)(0xFFFFFFFFu - (unsigned)(bv & 0xFFFFFFFFu));
    }
    sM = sPv[0];                            // global row max
  }

  // ---- bin selection: largest bin B with cum-from-top >= 56 ----
  const int b_lo = 2 * t, b_hi = 2 * t + 1;
  const unsigned h_lo = hist[0][b_lo] + hist[1][b_lo] + hist[2][b_lo] + hist[3][b_lo];
  const unsigned h_hi = hist[0][b_hi] + hist[1][b_hi] + hist[2][b_hi] + hist[3][b_hi];
  ubuf[t] = h_lo + h_hi;
  __syncthreads();
  for (int off = 1; off < 1024; off <<= 1) {
    const unsigned a = ubuf[t];
    const unsigned c = (t + off < 1024) ? ubuf[t + off] : 0u;
    __syncthreads();
    ubuf[t] = a + c;
    __syncthreads();
  }
  const unsigned above = (t < 1023) ? ubuf[t + 1] : 0u;
  const unsigned cum_hi = above + h_hi;
  const unsigned cum_lo = cum_hi + h_lo;
  if (cum_lo >= 56u) atomicMax(&selB, (cum_hi >= 56u) ? b_hi : b_lo);
  __syncthreads();
  const unsigned B1 = (unsigned)selB;

  // ---- scan 2: collect candidates (bin >= B1) ----
  #pragma unroll
  for (int it = 0; it < 12; ++it) {
    const int i = t * 4 + it * 4096;
    const float4 v = *(const float4*)(row + i);
    const float vv[4] = {v.x, v.y, v.z, v.w};
    #pragma unroll
    for (int e = 0; e < 4; ++e) {
      const unsigned u = f2u(vv[e]);
      if ((u >> 21) >= B1) {
        const unsigned pos = atomicAdd(&scnt, 1u);
        if (pos < 1024u) { candU[pos] = u; candI[pos] = i + e; }
      }
    }
  }
  __syncthreads();
  const int C = (int)min(scnt, 1024u);
  const float m = sM;

  // ---- part 1: 6 assoc logits + exact top-50 negatives (assoc excluded) ----
  int a6[6];
  {
    const int* ar = assoc + (size_t)plabel[b] * 6;
    #pragma unroll
    for (int e = 0; e < 6; ++e) a6[e] = ar[e];
  }
  float s1 = 0.f;
  if (t < C) {
    const unsigned u = candU[t]; const int ii = candI[t];
    bool ex = false;
    #pragma unroll
    for (int e = 0; e < 6; ++e) ex = ex || (ii == a6[e]);
    if (!ex) {
      int rank = 0;
      for (int j = 0; j < C; ++j) {
        const unsigned u2 = candU[j]; const int i2 = candI[j];
        bool ex2 = false;
        #pragma unroll
        for (int e = 0; e < 6; ++e) ex2 = ex2 || (i2 == a6[e]);
        if (!ex2 && (u2 > u || (u2 == u && i2 < ii))) ++rank;
      }
      if (rank < 50) s1 = __expf((u2f(u) - m) * INV_BETA);
    }
  }
  const float S1n = blk_sum1024(s1, rbuf, t);
  if (t == 0) {
    float S = S1n, am = 0.f;
    #pragma unroll
    for (int e = 0; e < 6; ++e) {
      const float va = row[a6[e]];
      S += __expf((va - m) * INV_BETA);
      am += va;
    }
    losses[BDIM + b] = m * INV_BETA + __logf(S) - am * (INV_BETA / 6.0f);
  }

  // ---- part 2: 3 positives + exact top-30 negatives (positives excluded) ----
  float s2 = 0.f;
  if (t < C) {
    const unsigned u = candU[t]; const int ii = candI[t];
    const bool ex = (ii == sPi[0]) || (ii == sPi[1]) || (ii == sPi[2]);
    if (!ex) {
      int rank = 0;
      for (int j = 0; j < C; ++j) {
        const unsigned u2 = candU[j]; const int i2 = candI[j];
        const bool ex2 = (i2 == sPi[0]) || (i2 == sPi[1]) || (i2 == sPi[2]);
        if (!ex2 && (u2 > u || (u2 == u && i2 < ii))) ++rank;
      }
      if (rank < 30) s2 = __expf((u2f(u) - m) * INV_BETA);
    }
  }
  const float S2n = blk_sum1024(s2, rbuf, t);
  if (t == 0) {
    const float p0 = sPv[0], p1 = sPv[1], p2 = sPv[2];
    const float S = S2n + 1.0f + __expf((p1 - m) * INV_BETA) + __expf((p2 - m) * INV_BETA);
    losses[2 * BDIM + b] = m * INV_BETA + __logf(S) - (p0 + p1 + p2) * (INV_BETA / 3.0f);
  }

  // ---- part 0: CE over own camera block ----
  const int mycam = cams[b];
  const float m0 = u2f((unsigned)(camKey[mycam] >> 32));
  const float* br = row + mycam * PDIM;
  float s0 = 0.f;
  #pragma unroll
  for (int it = 0; it < 2; ++it) {
    const int i = t * 4 + it * 4096;
    const float4 v = *(const float4*)(br + i);
    s0 += __expf((v.x - m0) * INV_BETA) + __expf((v.y - m0) * INV_BETA) +
          __expf((v.z - m0) * INV_BETA) + __expf((v.w - m0) * INV_BETA);
  }
  const float S0 = blk_sum1024(s0, rbuf, t);
  if (t == 0)
    losses[b] = m0 * INV_BETA + __logf(S0) - row[proxy[b]] * INV_BETA;
}

// ----------------------------------------------------------- finalize ----
__global__ __launch_bounds__(256) void final_kernel(
    const float* __restrict__ losses, const int* __restrict__ cams,
    float* __restrict__ out)
{
  __shared__ float s0[NCAMS], s1[NCAMS], s2[NCAMS];
  __shared__ int cnt[NCAMS];
  const int t = threadIdx.x;
  if (t < NCAMS) { s0[t] = 0.f; s1[t] = 0.f; s2[t] = 0.f; cnt[t] = 0; }
  __syncthreads();
  const int c = cams[t];
  atomicAdd(&s0[c], losses[t]);
  atomicAdd(&s1[c], losses[BDIM + t]);
  atomicAdd(&s2[c], losses[2 * BDIM + t]);
  atomicAdd(&cnt[c], 1);
  __syncthreads();
  if (t == 0) {
    float L = 0.f;
    for (int i = 0; i < NCAMS; ++i) {
      if (cnt[i] > 0) {
        const float ic = 1.0f / (float)cnt[i];
        L += 0.6f * s0[i] * ic + 0.7f * s1[i] * ic + 0.7f * s2[i] * ic;
      }
    }
    out[0] = L;
  }
}

extern "C" void kernel_launch(void* const* d_in, const int* in_sizes, int n_in,
                              void* d_out, int out_size, void* d_ws, size_t ws_size,
                              hipStream_t stream) {
  const float* feat   = (const float*)d_in[0];
  const float* bank   = (const float*)d_in[1];
  const int*   plabel = (const int*)d_in[2];
  const int*   proxy  = (const int*)d_in[3];
  const int*   cams   = (const int*)d_in[4];
  const int*   assoc  = (const int*)d_in[5];
  float* out = (float*)d_out;

  float* sims   = (float*)d_ws;                          // 50.3 MB
  float* losses = sims + (size_t)BDIM * MDIM;            // 3*256 fp32
  unsigned short* featb = (unsigned short*)(losses + 3 * BDIM);  // 1 MB bf16

  conv_feat<<<dim3((BDIM * DDIM) / 1024), 256, 0, stream>>>(feat, featb);
  gemm_kernel<<<dim3(MDIM / 64), 256, 0, stream>>>(featb, bank, sims);
  row_kernel<<<dim3(BDIM), 1024, 0, stream>>>(sims, plabel, proxy, cams, assoc, losses);
  final_kernel<<<1, 256, 0, stream>>>(losses, cams, out);
}

// Round 3
// 590.759 us; speedup vs baseline: 1.7458x; 1.1320x over previous
//
#include <hip/hip_runtime.h>

#define MDIM 49152
#define BDIM 256
#define DDIM 2048
#define PDIM 8192
#define NCAMS 6
#define INV_BETA 20.0f

typedef __attribute__((ext_vector_type(8))) short bf16x8;
typedef __attribute__((ext_vector_type(4))) float f32x4;

static __device__ __forceinline__ unsigned short f2bf(float f) {
  unsigned u = __float_as_uint(f);
  unsigned r = 0x7FFFu + ((u >> 16) & 1u);
  return (unsigned short)((u + r) >> 16);
}

// monotonic float->uint (larger float => larger uint), and inverse
static __device__ __forceinline__ unsigned f2u(float f) {
  unsigned u = __float_as_uint(f);
  return (u & 0x80000000u) ? ~u : (u | 0x80000000u);
}
static __device__ __forceinline__ float u2f(unsigned u) {
  return __uint_as_float((u & 0x80000000u) ? (u & 0x7FFFFFFFu) : ~u);
}

static __device__ __forceinline__ void gload_lds16(void* lds, const void* g) {
  __builtin_amdgcn_global_load_lds((const __attribute__((address_space(1))) unsigned int*)g,
                                   (__attribute__((address_space(3))) unsigned int*)lds,
                                   16, 0, 0);
}

// ------------------------------------------------ feat fp32 -> bf16 ----
__global__ __launch_bounds__(256) void conv_feat(
    const float* __restrict__ feat, unsigned short* __restrict__ fb)
{
  const int i = (blockIdx.x * 256 + threadIdx.x) * 4;
  const float4 v = *(const float4*)(feat + i);
  ushort4 p;
  p.x = f2bf(v.x); p.y = f2bf(v.y); p.z = f2bf(v.z); p.w = f2bf(v.w);
  *(ushort4*)(fb + i) = p;
}

// ---------------------------------------------------------------- GEMM ----
// sims[b][m] = feat[b,:] . bank[m,:].  BM=256 (bank read exactly once),
// BN=64, BK=64.  A via global_load_lds(16B); B fp32 reg-double-buffered,
// cvt->LDS.  Next-B loads issued after barrier so the vmcnt drain lands on
// the post-MFMA barrier (latency hidden behind 32 MFMAs).
__global__ __launch_bounds__(256) void gemm_kernel(
    const unsigned short* __restrict__ featb, const float* __restrict__ bank,
    float* __restrict__ sims)
{
  __shared__ unsigned short As[256][64];   // 32 KB
  __shared__ unsigned short Bs[64][64];    // 8 KB

  const int colTile = blockIdx.x * 64;     // bank rows
  const int t = threadIdx.x;
  const int lane = t & 63;
  const int w = t >> 6;                    // wave 0..3 -> A rows [w*64, w*64+64)
  const int fr = lane & 15;
  const int quad = lane >> 4;
  const int tr = t >> 4;                   // 0..15
  const int tkf = (t & 15) * 4;            // float col offset

  const int arow = w * 64 + (lane >> 3);   // + q*8
  const int acol = (lane & 7) * 8;         // bf16 col offset (16B granules)

  f32x4 acc[4][4];
  #pragma unroll
  for (int i = 0; i < 4; ++i)
    #pragma unroll
    for (int j = 0; j < 4; ++j)
      acc[i][j] = (f32x4){0.f, 0.f, 0.f, 0.f};

  float4 vb[4];
  #pragma unroll
  for (int p = 0; p < 4; ++p)
    vb[p] = *(const float4*)(bank + (size_t)(colTile + p * 16 + tr) * DDIM + tkf);

  for (int kc = 0; kc < DDIM; kc += 64) {
    // A: each wave DMAs its own 64x64 bf16 sub-tile
    #pragma unroll
    for (int q = 0; q < 8; ++q)
      gload_lds16(&As[w * 64 + q * 8][0],
                  featb + (size_t)(arow + q * 8) * DDIM + kc + acol);
    // B: cvt the prefetched fp32 tile into LDS
    #pragma unroll
    for (int p = 0; p < 4; ++p) {
      ushort4 pb;
      pb.x = f2bf(vb[p].x); pb.y = f2bf(vb[p].y);
      pb.z = f2bf(vb[p].z); pb.w = f2bf(vb[p].w);
      *(ushort4*)(&Bs[p * 16 + tr][tkf]) = pb;
    }
    __syncthreads();
    // prefetch next B tile (drained at the post-MFMA barrier)
    if (kc + 64 < DDIM) {
      #pragma unroll
      for (int p = 0; p < 4; ++p)
        vb[p] = *(const float4*)(bank + (size_t)(colTile + p * 16 + tr) * DDIM + kc + 64 + tkf);
    }
    #pragma unroll
    for (int kk = 0; kk < 64; kk += 32) {
      bf16x8 fa[4], fb[4];
      #pragma unroll
      for (int i = 0; i < 4; ++i)
        fa[i] = *(const bf16x8*)(&As[w * 64 + i * 16 + fr][kk + quad * 8]);
      #pragma unroll
      for (int j = 0; j < 4; ++j)
        fb[j] = *(const bf16x8*)(&Bs[j * 16 + fr][kk + quad * 8]);
      #pragma unroll
      for (int i = 0; i < 4; ++i)
        #pragma unroll
        for (int j = 0; j < 4; ++j)
          acc[i][j] = __builtin_amdgcn_mfma_f32_16x16x32_bf16(fa[i], fb[j], acc[i][j], 0, 0, 0);
    }
    __syncthreads();
  }

  #pragma unroll
  for (int i = 0; i < 4; ++i) {
    const int row0 = w * 64 + i * 16 + quad * 4;
    #pragma unroll
    for (int j = 0; j < 4; ++j) {
      const int col = colTile + j * 16 + fr;
      #pragma unroll
      for (int r = 0; r < 4; ++r)
        sims[(size_t)(row0 + r) * MDIM + col] = acc[i][j][r];
    }
  }
}

// ------------------------------------------------------------ per-row ----
static __device__ __forceinline__ float blk_sum1024(float v, float* buf, int t) {
  buf[t] = v; __syncthreads();
  for (int s = 512; s > 0; s >>= 1) {
    if (t < s) buf[t] += buf[t + s];
    __syncthreads();
  }
  const float r = buf[0]; __syncthreads();
  return r;
}

// One 1024-thread block per row.  Fast path: ONE vectorized scan collects
// all candidates >= 2.75 (exhaustive above threshold => top-56 provably
// contained when scnt >= 65) + per-cam argmax.  Exact radix-histogram
// fallback if the filter under/over-collects (never on this data).
__global__ __launch_bounds__(1024) void row_kernel(
    const float* __restrict__ sims, const int* __restrict__ plabel,
    const int* __restrict__ proxy, const int* __restrict__ cams,
    const int* __restrict__ assoc, float* __restrict__ losses)
{
  __shared__ unsigned hist[4][2048];       // 32 KB (fallback only)
  __shared__ unsigned candU[1024];         // 4 KB
  __shared__ int candI[1024];              // 4 KB
  __shared__ unsigned ubuf[1024];          // 4 KB (fallback suffix scan)
  __shared__ float rbuf[1024];             // 4 KB
  __shared__ unsigned long long camKey[NCAMS];
  __shared__ unsigned scnt;
  __shared__ int selB;
  __shared__ float sPv[3];
  __shared__ int sPi[3];

  const int b = blockIdx.x;
  const int t = threadIdx.x;
  const float* row = sims + (size_t)b * MDIM;

  if (t < NCAMS) camKey[t] = 0ull;
  if (t == 0) { scnt = 0u; selB = 0; }
  __syncthreads();

  const unsigned UC = f2u(2.75f);          // candidate filter
  const unsigned UPOS = 0x80000000u;       // v > 0 (argmax tracking filter)

  // ---- scan 1: candidates + per-cam argmax ----
  unsigned cmU[NCAMS] = {0, 0, 0, 0, 0, 0};
  int cmI[NCAMS] = {0, 0, 0, 0, 0, 0};
  #pragma unroll
  for (int it = 0; it < 12; ++it) {
    const int i = t * 4 + it * 4096;
    const float4 v = *(const float4*)(row + i);
    const float vv[4] = {v.x, v.y, v.z, v.w};
    unsigned bu = 0; int bi = i;
    #pragma unroll
    for (int e = 0; e < 4; ++e) {
      const unsigned u = f2u(vv[e]);
      if (u >= UC) {
        const unsigned pos = atomicAdd(&scnt, 1u);
        if (pos < 1024u) { candU[pos] = u; candI[pos] = i + e; }
      }
      if (u > UPOS && u > bu) { bu = u; bi = i + e; }
    }
    if (bu) {
      const int c = i >> 13;               // cam uniform within a float4
      #pragma unroll
      for (int cc = 0; cc < NCAMS; ++cc)
        if (cc == c && bu > cmU[cc]) { cmU[cc] = bu; cmI[cc] = bi; }
    }
  }
  // wave-reduce cam keys, one LDS atomic per wave per cam
  #pragma unroll
  for (int cc = 0; cc < NCAMS; ++cc) {
    unsigned long long k = ((unsigned long long)cmU[cc] << 32) |
                           (unsigned long long)(0xFFFFFFFFu - (unsigned)cmI[cc]);
    #pragma unroll
    for (int off = 32; off; off >>= 1) {
      const unsigned long long o = __shfl_down(k, off, 64);
      if (o > k) k = o;
    }
    if ((t & 63) == 0 && (k >> 32)) atomicMax(&camKey[cc], k);
  }
  __syncthreads();

  // ---- positives: top-3 cam maxima (value desc, lower index on ties) ----
  if (t == 0) {
    unsigned long long k[NCAMS];
    #pragma unroll
    for (int c = 0; c < NCAMS; ++c) k[c] = camKey[c];
    unsigned used = 0;
    for (int r = 0; r < 3; ++r) {
      int best = 0; unsigned long long bv = 0ull;
      for (int c = 0; c < NCAMS; ++c)
        if (!((used >> c) & 1u) && k[c] > bv) { bv = k[c]; best = c; }
      used |= 1u << best;
      sPv[r] = u2f((unsigned)(bv >> 32));
      sPi[r] = (int)(0xFFFFFFFFu - (unsigned)(bv & 0xFFFFFFFFu));
    }
  }
  __syncthreads();

  // ---- exactness fallback: filter under/over-collected (never on this data) ----
  if (scnt < 65u || scnt > 1024u) {
    for (int i = t; i < 4 * 2048; i += 1024) ((unsigned*)hist)[i] = 0u;
    __syncthreads();
    const int copy = t >> 8;
    #pragma unroll
    for (int it = 0; it < 12; ++it) {
      const int i = t * 4 + it * 4096;
      const float4 v = *(const float4*)(row + i);
      const float vv[4] = {v.x, v.y, v.z, v.w};
      #pragma unroll
      for (int e = 0; e < 4; ++e)
        atomicAdd(&hist[copy][f2u(vv[e]) >> 21], 1u);
    }
    __syncthreads();
    const int b_lo = 2 * t, b_hi = 2 * t + 1;
    const unsigned h_lo = hist[0][b_lo] + hist[1][b_lo] + hist[2][b_lo] + hist[3][b_lo];
    const unsigned h_hi = hist[0][b_hi] + hist[1][b_hi] + hist[2][b_hi] + hist[3][b_hi];
    ubuf[t] = h_lo + h_hi;
    __syncthreads();
    for (int off = 1; off < 1024; off <<= 1) {
      const unsigned a = ubuf[t];
      const unsigned c = (t + off < 1024) ? ubuf[t + off] : 0u;
      __syncthreads();
      ubuf[t] = a + c;
      __syncthreads();
    }
    const unsigned above = (t < 1023) ? ubuf[t + 1] : 0u;
    const unsigned cum_hi = above + h_hi;
    const unsigned cum_lo = cum_hi + h_lo;
    if (cum_lo >= 56u) atomicMax(&selB, (cum_hi >= 56u) ? b_hi : b_lo);
    if (t == 0) scnt = 0u;
    __syncthreads();
    const unsigned B1 = (unsigned)selB;
    #pragma unroll
    for (int it = 0; it < 12; ++it) {
      const int i = t * 4 + it * 4096;
      const float4 v = *(const float4*)(row + i);
      const float vv[4] = {v.x, v.y, v.z, v.w};
      #pragma unroll
      for (int e = 0; e < 4; ++e) {
        const unsigned u = f2u(vv[e]);
        if ((u >> 21) >= B1) {
          const unsigned pos = atomicAdd(&scnt, 1u);
          if (pos < 1024u) { candU[pos] = u; candI[pos] = i + e; }
        }
      }
    }
    __syncthreads();
  }

  const int C = (int)min(scnt, 1024u);
  const float m = sPv[0];                   // global row max

  // ---- part 1: 6 assoc logits + exact top-50 negatives (assoc excluded) ----
  int a6[6];
  {
    const int* ar = assoc + (size_t)plabel[b] * 6;
    #pragma unroll
    for (int e = 0; e < 6; ++e) a6[e] = ar[e];
  }
  float s1 = 0.f;
  if (t < C) {
    const unsigned u = candU[t]; const int ii = candI[t];
    bool ex = false;
    #pragma unroll
    for (int e = 0; e < 6; ++e) ex = ex || (ii == a6[e]);
    if (!ex) {
      int rank = 0;
      for (int j = 0; j < C; ++j) {
        const unsigned u2 = candU[j]; const int i2 = candI[j];
        bool ex2 = false;
        #pragma unroll
        for (int e = 0; e < 6; ++e) ex2 = ex2 || (i2 == a6[e]);
        if (!ex2 && (u2 > u || (u2 == u && i2 < ii))) ++rank;
      }
      if (rank < 50) s1 = __expf((u2f(u) - m) * INV_BETA);
    }
  }
  const float S1n = blk_sum1024(s1, rbuf, t);
  if (t == 0) {
    float S = S1n, am = 0.f;
    #pragma unroll
    for (int e = 0; e < 6; ++e) {
      const float va = row[a6[e]];
      S += __expf((va - m) * INV_BETA);
      am += va;
    }
    losses[BDIM + b] = m * INV_BETA + __logf(S) - am * (INV_BETA / 6.0f);
  }

  // ---- part 2: 3 positives + exact top-30 negatives (positives excluded) ----
  float s2 = 0.f;
  if (t < C) {
    const unsigned u = candU[t]; const int ii = candI[t];
    const bool ex = (ii == sPi[0]) || (ii == sPi[1]) || (ii == sPi[2]);
    if (!ex) {
      int rank = 0;
      for (int j = 0; j < C; ++j) {
        const unsigned u2 = candU[j]; const int i2 = candI[j];
        const bool ex2 = (i2 == sPi[0]) || (i2 == sPi[1]) || (i2 == sPi[2]);
        if (!ex2 && (u2 > u || (u2 == u && i2 < ii))) ++rank;
      }
      if (rank < 30) s2 = __expf((u2f(u) - m) * INV_BETA);
    }
  }
  const float S2n = blk_sum1024(s2, rbuf, t);
  if (t == 0) {
    const float p0 = sPv[0], p1 = sPv[1], p2 = sPv[2];
    const float S = S2n + 1.0f + __expf((p1 - m) * INV_BETA) + __expf((p2 - m) * INV_BETA);
    losses[2 * BDIM + b] = m * INV_BETA + __logf(S) - (p0 + p1 + p2) * (INV_BETA / 3.0f);
  }

  // ---- part 0: CE over own camera block ----
  const int mycam = cams[b];
  float m0;
  if (camKey[mycam] != 0ull) {
    m0 = u2f((unsigned)(camKey[mycam] >> 32));
  } else {
    // exactness fallback: cam max <= 0 (never on this data)
    float lm = -3.4e38f;
    const float* br = row + mycam * PDIM;
    for (int i = t; i < PDIM; i += 1024) lm = fmaxf(lm, br[i]);
    rbuf[t] = lm; __syncthreads();
    for (int s = 512; s > 0; s >>= 1) {
      if (t < s) rbuf[t] = fmaxf(rbuf[t], rbuf[t + s]);
      __syncthreads();
    }
    m0 = rbuf[0]; __syncthreads();
  }
  const float* br = row + mycam * PDIM;
  float s0 = 0.f;
  #pragma unroll
  for (int it = 0; it < 2; ++it) {
    const int i = t * 4 + it * 4096;
    const float4 v = *(const float4*)(br + i);
    s0 += __expf((v.x - m0) * INV_BETA) + __expf((v.y - m0) * INV_BETA) +
          __expf((v.z - m0) * INV_BETA) + __expf((v.w - m0) * INV_BETA);
  }
  const float S0 = blk_sum1024(s0, rbuf, t);
  if (t == 0)
    losses[b] = m0 * INV_BETA + __logf(S0) - row[proxy[b]] * INV_BETA;
}

// ----------------------------------------------------------- finalize ----
__global__ __launch_bounds__(256) void final_kernel(
    const float* __restrict__ losses, const int* __restrict__ cams,
    float* __restrict__ out)
{
  __shared__ float s0[NCAMS], s1[NCAMS], s2[NCAMS];
  __shared__ int cnt[NCAMS];
  const int t = threadIdx.x;
  if (t < NCAMS) { s0[t] = 0.f; s1[t] = 0.f; s2[t] = 0.f; cnt[t] = 0; }
  __syncthreads();
  const int c = cams[t];
  atomicAdd(&s0[c], losses[t]);
  atomicAdd(&s1[c], losses[BDIM + t]);
  atomicAdd(&s2[c], losses[2 * BDIM + t]);
  atomicAdd(&cnt[c], 1);
  __syncthreads();
  if (t == 0) {
    float L = 0.f;
    for (int i = 0; i < NCAMS; ++i) {
      if (cnt[i] > 0) {
        const float ic = 1.0f / (float)cnt[i];
        L += 0.6f * s0[i] * ic + 0.7f * s1[i] * ic + 0.7f * s2[i] * ic;
      }
    }
    out[0] = L;
  }
}

extern "C" void kernel_launch(void* const* d_in, const int* in_sizes, int n_in,
                              void* d_out, int out_size, void* d_ws, size_t ws_size,
                              hipStream_t stream) {
  const float* feat   = (const float*)d_in[0];
  const float* bank   = (const float*)d_in[1];
  const int*   plabel = (const int*)d_in[2];
  const int*   proxy  = (const int*)d_in[3];
  const int*   cams   = (const int*)d_in[4];
  const int*   assoc  = (const int*)d_in[5];
  float* out = (float*)d_out;

  float* sims   = (float*)d_ws;                          // 50.3 MB
  float* losses = sims + (size_t)BDIM * MDIM;            // 3*256 fp32
  unsigned short* featb = (unsigned short*)(losses + 3 * BDIM);  // 1 MB bf16

  conv_feat<<<dim3((BDIM * DDIM) / 1024), 256, 0, stream>>>(feat, featb);
  gemm_kernel<<<dim3(MDIM / 64), 256, 0, stream>>>(featb, bank, sims);
  row_kernel<<<dim3(BDIM), 1024, 0, stream>>>(sims, plabel, proxy, cams, assoc, losses);
  final_kernel<<<1, 256, 0, stream>>>(losses, cams, out);
}